// Round 5
// baseline (530.951 us; speedup 1.0000x reference)
//
#include <hip/hip_runtime.h>
#include <stdint.h>

#define EPSV 1e-5f

// c8-chunked activation layout: elem = cc*278784 + ((b*66+y)*66+x)*8 + (c&7)
#define CPLANE 278784   // 8*66*66*8 elems per channel-chunk plane

using floatx4 = __attribute__((ext_vector_type(4))) float;
using short8  = __attribute__((ext_vector_type(8))) short;

// async global->LDS 16B DMA: data lands at ldsbase + lane*16
#define GLD(gp, lp) __builtin_amdgcn_global_load_lds( \
    (const __attribute__((address_space(1))) void*)(gp), \
    (__attribute__((address_space(3))) void*)(lp), 16, 0, 0)

__device__ __forceinline__ unsigned short f2bf(float f) {
  union { float f; unsigned int u; } x; x.f = f;
  unsigned int r = x.u + 0x7fffu + ((x.u >> 16) & 1u);  // RNE
  return (unsigned short)(r >> 16);
}

// ---------------------------------------------------------------------------
// Zero the halo border of both padded c8 buffers (2.13 MB each).
// ---------------------------------------------------------------------------
__global__ __launch_bounds__(256) void border_zero_kernel(
    unsigned short* __restrict__ Xp0, unsigned short* __restrict__ Xp1) {
  int idx = blockIdx.x * 256 + threadIdx.x;   // 520*256 = 133120 = 8*64*260
  int k = idx % 260;
  int rest = idx / 260;
  int cc = rest & 63;
  int b = rest >> 6;
  int py, px;
  if (k < 66)       { py = 0;  px = k; }
  else if (k < 132) { py = 65; px = k - 66; }
  else { int k2 = k - 132; py = 1 + (k2 >> 1); px = (k2 & 1) ? 65 : 0; }
  int off = cc * CPLANE + ((b * 66 + py) * 66 + px) * 8;
  short8 z = {};
  *(short8*)(Xp0 + off) = z;
  *(short8*)(Xp1 + off) = z;
}

// ---------------------------------------------------------------------------
// Upsample (align-corners bilinear 32->64) + alpha*xm fuse -> bf16 c8 layout.
// ---------------------------------------------------------------------------
__global__ __launch_bounds__(256) void fuse_upsample_kernel(
    const float* __restrict__ xt, const float* __restrict__ xm,
    const float* __restrict__ alpha, unsigned short* __restrict__ Xp) {
  __shared__ float sm[32 * 66];        // xm tile [c][x], pad 66
  __shared__ float st[2 * 32 * 34];    // xt rows [h][c][x0..31], pad 34

  const int tid = threadIdx.x;
  const int ct = blockIdx.x & 15;          // channel tile (32 ch)
  const int y  = (blockIdx.x >> 4) & 63;
  const int b  = blockIdx.x >> 10;
  const int c0 = ct * 32;

  const float fy = y * (31.0f / 63.0f);
  const int y0 = (int)fy;
  const float wy = fy - (float)y0;
  const int y1 = min(y0 + 1, 31);

  // phase 1: xm tile, lane = x (coalesced 256B rows)
  {
    const int cb = (tid >> 6) * 8;
    const int xi = tid & 63;
#pragma unroll
    for (int j = 0; j < 8; ++j) {
      int c = cb + j;
      sm[c * 66 + xi] = xm[(((b << 9) + c0 + c) << 12) + (y << 6) + xi];
    }
  }
  // phase 2: xt rows y0,y1 (32 x-contiguous floats per (h,c) -> coalesced)
#pragma unroll
  for (int j = 0; j < 8; ++j) {
    int idx = j * 256 + tid;
    int xi = idx & 31, cc = (idx >> 5) & 31, h = idx >> 10;
    int yr = h ? y1 : y0;
    st[h * 1088 + cc * 34 + xi] =
        xt[(((b << 9) + c0 + cc) << 10) + (yr << 5) + xi];
  }
  __syncthreads();

  // phase 3: interpolate + fuse, write one c8 chunk per thread
  const float a = alpha[0];
  const int xo = tid & 63;
  const int cl = tid >> 6;             // local cchunk 0..3
  const float fx = xo * (31.0f / 63.0f);
  const int x0 = (int)fx;
  const float wx = fx - (float)x0;
  const int x1 = min(x0 + 1, 31);
  short8 ov;
#pragma unroll
  for (int j = 0; j < 8; ++j) {
    int c = cl * 8 + j;
    float t0 = st[c * 34 + x0], t1 = st[c * 34 + x1];
    float u0 = st[1088 + c * 34 + x0], u1 = st[1088 + c * 34 + x1];
    float top = t0 * (1.0f - wx) + t1 * wx;
    float bot = u0 * (1.0f - wx) + u1 * wx;
    float up = top * (1.0f - wy) + bot * wy;
    float val = up + a * sm[c * 66 + xo];
    ov[j] = (short)f2bf(val);
  }
  *(short8*)(Xp + ((c0 >> 3) + cl) * CPLANE +
             ((b * 66 + y + 1) * 66 + xo + 1) * 8) = ov;
}

// ---------------------------------------------------------------------------
// Repack weights OIHW fp32 -> [tap][cinchunk][cout][8] bf16 via LDS transpose.
// ---------------------------------------------------------------------------
template <int COUT>
__global__ __launch_bounds__(256) void prep_w_kernel(
    const float* __restrict__ w, unsigned short* __restrict__ Wg) {
  __shared__ unsigned short l[4608];   // [tap][cin]
  const int o = blockIdx.x, t = threadIdx.x;
  const float* src = w + o * 4608;
#pragma unroll
  for (int j = 0; j < 18; ++j) {
    int idx = j * 256 + t;             // = i*9 + tap
    l[(idx % 9) * 512 + idx / 9] = f2bf(src[idx]);
  }
  __syncthreads();
#pragma unroll
  for (int tap = 0; tap < 9; ++tap) {
    int cc = t >> 2;
    int off = ((tap * 64 + cc) * COUT + o) * 8 + ((2 * t) & 7);
    *(unsigned int*)(Wg + off) = *(const unsigned int*)(l + (tap << 9) + 2 * t);
  }
}

// ---------------------------------------------------------------------------
// Implicit-GEMM 3x3 conv + BN + ReLU — wide-wave-tile, barrier-free tap loop.
// Input : c8 bf16 [64cc][8b][66][66][8] ; weights [9][64cc][COUT][8] bf16
// Block: 4 waves, wave tile = (MI*16) pixels x 128 couts.
//   - A tile (activations, with x/y halo) staged in LDS once per c-group
//     (64 ch); the 9 taps read shifted windows -> NO per-tap barriers.
//   - B fragments (weights) read DIRECTLY from global per MFMA: each lane's
//     16B frag is contiguous; all 4 waves + co-resident block (ctile-major
//     grid) hit identical addresses -> L1-served. Operand BW is thus split
//     LDS (A, ~32 B/cyc) + L1 (B) instead of all-LDS (was the ~85 B/cyc
//     ceiling that capped round 4 at MfmaUtil 44%).
// ---------------------------------------------------------------------------
template <int COUT, int MI, bool FINAL>
__global__ __launch_bounds__(256, 2) void conv3x3_kernel(
    const unsigned short* __restrict__ Xp, const unsigned short* __restrict__ Wg,
    const float* __restrict__ gamma, const float* __restrict__ beta,
    const float* __restrict__ mean, const float* __restrict__ var,
    unsigned short* __restrict__ OutPad, float* __restrict__ OutF) {
  constexpr int ROWS = MI + 2;               // staged input rows (halo incl.)
  constexpr int NPT  = 32768 / (MI * 64);    // pixel tiles
  __shared__ unsigned short Abuf[8 * ROWS * 528];  // [kc][row][66][8]

  const int tid = threadIdx.x;
  const int ctile = (int)blockIdx.x / NPT;   // ctile-major: residents share B
  const int ptile = (int)blockIdx.x % NPT;
  const int p0 = ptile * (MI * 64);
  const int w = tid >> 6;
  const int lane = tid & 63;
  const int fi = lane & 15;
  const int kc = lane >> 4;

  const int pb = p0 >> 12;                   // batch
  const int yb = (p0 >> 6) & 63;             // first padded input row
  const int ywave = (w * MI * 16) >> 6;      // wave's y row within block
  const int xbase = (w * MI * 16) & 63;      // wave's x base within row

  // staging: wave w owns kc chunks {2w, 2w+1}; lane = x chunk
  const unsigned short* Ag = Xp + ((pb * 66 + yb) * 66) * 8 + lane * 8;
  unsigned short* Ad = Abuf + (2 * w) * (ROWS * 528);

  // fragment bases
  const unsigned short* Afrag =
      Abuf + kc * (ROWS * 528) + (ywave + 1) * 528 + (xbase + fi + 1) * 8;
  const unsigned short* Wlane = Wg + (ctile * 128 + fi) * 8 + kc * (COUT * 8);

  floatx4 acc[MI][8] = {};

  for (int cg = 0; cg < 8; ++cg) {
    __syncthreads();                         // protect A readers of prev cg
#pragma unroll
    for (int kk = 0; kk < 2; ++kk) {
      const unsigned short* g = Ag + (cg * 8 + 2 * w + kk) * CPLANE;
      unsigned short* d = Ad + kk * (ROWS * 528);
#pragma unroll
      for (int r = 0; r < ROWS; ++r) {
        GLD(g + r * 528,      d + r * 528);       // x chunks 0..63
        GLD(g + r * 528 + 16, d + r * 528 + 16);  // x chunks 2..65
      }
    }
    __syncthreads();                         // DMA drained, A visible

#pragma unroll
    for (int tap = 0; tap < 9; ++tap) {
      const int dy = tap / 3 - 1;
      const int dx = tap % 3 - 1;
      const unsigned short* Wt = Wlane + ((tap * 64 + cg * 8) * COUT) * 8;
      short8 bt[2][8];
#pragma unroll
      for (int t = 0; t < 2; ++t)
#pragma unroll
        for (int ni = 0; ni < 8; ++ni)
          bt[t][ni] = *(const short8*)(Wt + (t * 4 * COUT + ni * 16) * 8);
#pragma unroll
      for (int t = 0; t < 2; ++t) {
        short8 af[MI];
#pragma unroll
        for (int mi = 0; mi < MI; ++mi)
          af[mi] = *(const short8*)(Afrag + t * (4 * ROWS * 528) + dy * 528 +
                                    (mi * 16 + dx) * 8);
#pragma unroll
        for (int mi = 0; mi < MI; ++mi)
#pragma unroll
          for (int ni = 0; ni < 8; ++ni)
            acc[mi][ni] = __builtin_amdgcn_mfma_f32_16x16x32_bf16(
                af[mi], bt[t][ni], acc[mi][ni], 0, 0, 0);
      }
    }
  }

  // ---- epilogue: BN + ReLU
  // C/D layout: col = lane&15 (=cout), row = (lane>>4)*4 + reg (=pixel)
#pragma unroll
  for (int ni = 0; ni < 8; ++ni) {
    const int co = ctile * 128 + ni * 16 + fi;
    const float sc = gamma[co] / sqrtf(var[co] + EPSV);
    const float sh2 = beta[co] - mean[co] * sc;
#pragma unroll
    for (int mi = 0; mi < MI; ++mi) {
      const int p = p0 + w * MI * 16 + mi * 16 + kc * 4;  // 4 consec pixels
      const int pbb = p >> 12;
      const int prem = p & 4095;
      if constexpr (FINAL) {
        floatx4 o;
#pragma unroll
        for (int r = 0; r < 4; ++r) o[r] = fmaxf(acc[mi][ni][r] * sc + sh2, 0.0f);
        *(floatx4*)(OutF + ((pbb * COUT + co) << 12) + prem) = o;  // NCHW fp32
      } else {
        const int py = prem >> 6, px = prem & 63;
        unsigned short* dst = OutPad + (co >> 3) * CPLANE +
            ((pbb * 66 + py + 1) * 66 + px + 1) * 8 + (co & 7);
#pragma unroll
        for (int r = 0; r < 4; ++r)
          dst[r * 8] = f2bf(fmaxf(acc[mi][ni][r] * sc + sh2, 0.0f));
      }
    }
  }
}

// ---------------------------------------------------------------------------
// workspace layout (bytes):
//   Xp0 : 0          .. 35684352   (64cc * 8*66*66 * 8 bf16)
//   Xp1 : 35684352   .. 71368704
//   Wg0 : 71368704   .. 76087296   (9*64*512*8 bf16)
//   Wg1 : 76087296   .. 78446592   (9*64*256*8 bf16)
// ---------------------------------------------------------------------------
extern "C" void kernel_launch(void* const* d_in, const int* in_sizes, int n_in,
                              void* d_out, int out_size, void* d_ws, size_t ws_size,
                              hipStream_t stream) {
  const float* xt    = (const float*)d_in[0];
  const float* xm    = (const float*)d_in[1];
  const float* alpha = (const float*)d_in[3];
  const float* w0    = (const float*)d_in[4];
  const float* g0    = (const float*)d_in[5];
  const float* b0    = (const float*)d_in[6];
  const float* m0    = (const float*)d_in[7];
  const float* v0    = (const float*)d_in[8];
  const float* w1    = (const float*)d_in[9];
  const float* g1    = (const float*)d_in[10];
  const float* b1    = (const float*)d_in[11];
  const float* m1    = (const float*)d_in[12];
  const float* v1    = (const float*)d_in[13];
  float* out = (float*)d_out;

  char* ws = (char*)d_ws;
  unsigned short* Xp0 = (unsigned short*)(ws);
  unsigned short* Xp1 = (unsigned short*)(ws + 35684352);
  unsigned short* Wg0 = (unsigned short*)(ws + 2 * 35684352);
  unsigned short* Wg1 = (unsigned short*)(ws + 2 * 35684352 + 4718592);

  border_zero_kernel<<<520, 256, 0, stream>>>(Xp0, Xp1);
  prep_w_kernel<512><<<512, 256, 0, stream>>>(w0, Wg0);
  prep_w_kernel<256><<<256, 256, 0, stream>>>(w1, Wg1);
  fuse_upsample_kernel<<<8192, 256, 0, stream>>>(xt, xm, alpha, Xp0);
  // conv0: wave 64px x 128co, 512 blocks (2/CU);  conv1: wave 32px x 128co
  conv3x3_kernel<512, 4, false><<<512, 256, 0, stream>>>(Xp0, Wg0, g0, b0, m0, v0, Xp1, nullptr);
  conv3x3_kernel<256, 2, true><<<512, 256, 0, stream>>>(Xp1, Wg1, g1, b1, m1, v1, nullptr, out);
}